// Round 15
// baseline (231.673 us; speedup 1.0000x reference)
//
#include <hip/hip_runtime.h>
#include <math.h>

// DVS forward: per-batch 6x6 normal-equation build + solve.
// B=64, image 512x640, border 5 -> interior rows [5,507), cols [5,635).
// R14 = R12 (best, 56.5us: RPT=8, 14-row reg window, branchless clamp dedup,
// XCD swizzle, 64-VGPR equilibrium) + FUSED last-block-per-batch solve tail:
// block stores its 27-float partial -> threadfence -> atomicAdd(counter[b]);
// the 48th block re-reads all partials (device-scope atomic loads) and does
// the f64 solve in LDS (no VGPR pressure on the hot loop). Eliminates the
// second kernel launch (~5-8us serial tail). Deterministic: summation order
// and GE are fixed regardless of which block arrives last.

namespace {
constexpr int HI = 512, WI = 640, BRD = 5;
constexpr int RPT = 8;                 // center rows per wave
constexpr int TILES = 64;              // tiles per (b,seg); 64*8=512>=502, tail masked
constexpr int WVS = 4;                 // waves per block
constexpr int BPS = TILES / WVS;       // 16 blocks per (b,seg)
constexpr int SEGS = 3;
constexpr int BLK_PER_B = SEGS * BPS;  // 48 partials per batch
constexpr float PXc = 600.0f, PYc = 600.0f, U0c = 320.0f, V0c = 256.0f;
constexpr float G1 = 2047.0f / 8418.0f * 600.0f;   // F*PX (PX==PY)
constexpr float G2 = 913.0f  / 8418.0f * 600.0f;
constexpr float G3 = 112.0f  / 8418.0f * 600.0f;
}

__device__ __forceinline__ float elem(const float4 v, int q) {
    return q == 0 ? v.x : (q == 1 ? v.y : (q == 2 ? v.z : v.w));
}

__global__ __launch_bounds__(256) void dvs_partial(
    const float* __restrict__ Is, const float* __restrict__ Ids,
    const float* __restrict__ Zinv, const float* __restrict__ mu,
    float* __restrict__ ws, int* __restrict__ cnt, float* __restrict__ out)
{
    const int tid  = threadIdx.x;
    const int lane = tid & 63;
    const int wv   = tid >> 6;
    // XCD-chunked bijective swizzle (grid % 8 == 0): chunk c -> XCD c.
    int wg = blockIdx.x;
    if ((gridDim.x & 7) == 0) {
        const int chunk = gridDim.x >> 3;
        wg = (blockIdx.x & 7) * chunk + (blockIdx.x >> 3);
    }
    const int b   = wg / BLK_PER_B;
    const int rem = wg - b * BLK_PER_B;
    const int seg = rem / BPS;
    const int bg  = rem - seg * BPS;
    const int tile = bg * WVS + wv;
    const int r0 = BRD + tile * RPT;             // center rows r0..r0+7 (masked)

    const int base = (seg == 0) ? 0   : ((seg == 1) ? 200 : 384);
    const int lo   = (seg == 0) ? 5   : ((seg == 1) ? 252 : 452);
    const int hi   = (seg == 0) ? 252 : ((seg == 1) ? 452 : 635);
    const int c0 = base + (lane << 2);

    // Branchless load-dedup addresses (R12): clamp wasted lanes into closure.
    const int cIds = min(max(c0, (lo - 3) & ~3), (hi + 2) & ~3);
    const int cIZ  = min(max(c0, lo & ~3), (hi - 1) & ~3);

    const size_t ofs = (size_t)b * (HI * WI);
    const float* __restrict__ Ib = Is   + ofs;
    const float* __restrict__ Db = Ids  + ofs;
    const float* __restrict__ Zb = Zinv + ofs;

    float msk[4], xk[4];
#pragma unroll
    for (int q = 0; q < 4; ++q) {
        const int c = c0 + q;
        msk[q] = (c >= lo && c < hi) ? 1.0f : 0.0f;
        xk[q]  = ((float)c - U0c) * (1.0f / PXc);
    }

    // ---- issue all 14 Ids window rows up front (independent addresses) ----
    float4 win[14];
#pragma unroll
    for (int j = 0; j < 14; ++j) {
        const int rr = min(r0 - 3 + j, HI - 1);
        win[j] = *(const float4*)(Db + rr * WI + cIds);
    }
    // Is/Zinv: 3-slot rotation, 2-row lookahead (static indices under unroll)
    float4 isb[3], zvb[3];
    {
        const int ra = min(r0, HI - 1);
        const int rb = min(r0 + 1, HI - 1);
        isb[0] = *(const float4*)(Ib + ra * WI + cIZ);
        zvb[0] = *(const float4*)(Zb + ra * WI + cIZ);
        isb[1] = *(const float4*)(Ib + rb * WI + cIZ);
        zvb[1] = *(const float4*)(Zb + rb * WI + cIZ);
    }
    isb[2] = isb[0]; zvb[2] = zvb[0];

    float acc[27];
#pragma unroll
    for (int t = 0; t < 27; ++t) acc[t] = 0.0f;

    const int lm = (lane + 63) & 63, lp = (lane + 1) & 63;

#pragma unroll
    for (int k = 0; k < RPT; ++k) {
        if (k < RPT - 2) {                        // prefetch row k+2 Is/Zinv
            const int rr = min(r0 + k + 2, HI - 1);
            isb[(k + 2) % 3] = *(const float4*)(Ib + rr * WI + cIZ);
            zvb[(k + 2) % 3] = *(const float4*)(Zb + rr * WI + cIZ);
        }
        const int rc = r0 + k;
        const float rmk = (rc < HI - BRD) ? 1.0f : 0.0f;
        const float4 a0 = win[k], a1 = win[k + 1], a2 = win[k + 2],
                     ct = win[k + 3], a4 = win[k + 4], a5 = win[k + 5],
                     a6 = win[k + 6];
        const float hl1 = __shfl(ct.w, lm);   // col c0-1
        const float hl2 = __shfl(ct.z, lm);   // col c0-2
        const float hl3 = __shfl(ct.y, lm);   // col c0-3
        const float hr1 = __shfl(ct.x, lp);   // col c0+4
        const float hr2 = __shfl(ct.y, lp);   // col c0+5
        const float hr3 = __shfl(ct.z, lp);   // col c0+6
        const float h[10] = {hl3, hl2, hl1, ct.x, ct.y, ct.z, ct.w,
                             hr1, hr2, hr3};
        const float yv  = ((float)rc - V0c) * (1.0f / PYc);
        const float4 isV = isb[k % 3], zV = zvb[k % 3];
#pragma unroll
        for (int q = 0; q < 4; ++q) {
            const float m  = msk[q] * rmk;
            const float Ix = fmaf(G3, h[q + 6] - h[q],
                              fmaf(G2, h[q + 5] - h[q + 1],
                                   G1 * (h[q + 4] - h[q + 2]))) * m;
            const float Iy = fmaf(G3, elem(a6, q) - elem(a0, q),
                              fmaf(G2, elem(a5, q) - elem(a1, q),
                                   G1 * (elem(a4, q) - elem(a2, q)))) * m;
            const float Z  = elem(zV, q);
            const float e  = elem(isV, q) - elem(ct, q);
            const float x  = xk[q], xy = x * yv;
            const float tt = x * Ix, uu = yv * Iy;
            float L[6];
            L[0] = Ix * Z;
            L[1] = Iy * Z;
            L[2] = -(tt + uu) * Z;
            L[3] = -(fmaf(yv, uu, Iy) + Ix * xy);   // -Ix*xy - (1+y^2)Iy
            L[4] = fmaf(x, tt, Ix) + Iy * xy;       // (1+x^2)Ix + Iy*xy
            L[5] = Iy * x - Ix * yv;
            int t = 0;
#pragma unroll
            for (int i = 0; i < 6; ++i)
#pragma unroll
                for (int j = i; j < 6; ++j)
                    acc[t++] += L[i] * L[j];
#pragma unroll
            for (int i = 0; i < 6; ++i) acc[21 + i] += L[i] * e;
        }
    }

    // wave butterfly reduce (deterministic)
#pragma unroll
    for (int t = 0; t < 27; ++t) {
        float v = acc[t];
        v += __shfl_xor(v, 1);  v += __shfl_xor(v, 2);  v += __shfl_xor(v, 4);
        v += __shfl_xor(v, 8);  v += __shfl_xor(v, 16); v += __shfl_xor(v, 32);
        acc[t] = v;
    }
    float outv = acc[0];
#pragma unroll
    for (int t = 1; t < 27; ++t) if (lane == t) outv = acc[t];

    __shared__ float red[WVS][28];
    if (lane < 27) red[wv][lane] = outv;
    __syncthreads();
    if (tid < 27) {
        float s = red[0][tid] + red[1][tid] + red[2][tid] + red[3][tid];
        ws[((size_t)b * BLK_PER_B + rem) * 27 + tid] = s;
    }

    // ---- fused solve tail: last block of batch b does the 6x6 solve ----
    __shared__ int lastFlag;
    __syncthreads();                              // ws writes done block-wide
    if (tid == 0) {
        __threadfence();                          // release partial to device
        const int old = __hip_atomic_fetch_add(&cnt[b], 1, __ATOMIC_ACQ_REL,
                                               __HIP_MEMORY_SCOPE_AGENT);
        lastFlag = (old == BLK_PER_B - 1) ? 1 : 0;
    }
    __syncthreads();
    if (lastFlag == 0) return;

    __shared__ double hsum[27];
    if (tid < 27) {                               // fixed order: deterministic
        double t = 0.0;
        const float* p = ws + (size_t)b * BLK_PER_B * 27 + tid;
        for (int s = 0; s < BLK_PER_B; ++s)
            t += (double)__hip_atomic_load(p + s * 27, __ATOMIC_RELAXED,
                                           __HIP_MEMORY_SCOPE_AGENT);
        hsum[tid] = t;
    }
    __syncthreads();
    if (tid == 0) {
        double A[6][7];
        int k = 0;
        for (int i = 0; i < 6; ++i)
            for (int j = i; j < 6; ++j) { A[i][j] = hsum[k]; A[j][i] = hsum[k]; ++k; }
        const double dm = 1.0 + (double)mu[b];
        for (int i = 0; i < 6; ++i) { A[i][i] *= dm; A[i][6] = hsum[21 + i]; }
        for (int col = 0; col < 6; ++col) {
            int p = col; double best = fabs(A[col][col]);
            for (int r = col + 1; r < 6; ++r) {
                const double vv = fabs(A[r][col]);
                if (vv > best) { best = vv; p = r; }
            }
            if (p != col)
                for (int cc = col; cc < 7; ++cc) {
                    const double t = A[col][cc]; A[col][cc] = A[p][cc]; A[p][cc] = t;
                }
            const double inv = 1.0 / A[col][col];
            for (int r = col + 1; r < 6; ++r) {
                const double f = A[r][col] * inv;
                for (int cc = col + 1; cc < 7; ++cc) A[r][cc] -= f * A[col][cc];
            }
        }
        double xs[6];
        for (int i = 5; i >= 0; --i) {
            double s = A[i][6];
            for (int j = i + 1; j < 6; ++j) s -= A[i][j] * xs[j];
            xs[i] = s / A[i][i];
        }
        for (int i = 0; i < 6; ++i) out[b * 6 + i] = (float)(-xs[i]);
    }
}

extern "C" void kernel_launch(void* const* d_in, const int* in_sizes, int n_in,
                              void* d_out, int out_size, void* d_ws, size_t ws_size,
                              hipStream_t stream)
{
    const float* Is   = (const float*)d_in[0];
    const float* Ids  = (const float*)d_in[1];
    const float* Zinv = (const float*)d_in[2];
    const float* mu   = (const float*)d_in[3];
    const int B = in_sizes[3];
    float* out = (float*)d_out;
    float* ws  = (float*)d_ws;
    int*   cnt = (int*)((char*)d_ws + (size_t)B * BLK_PER_B * 27 * sizeof(float));

    hipMemsetAsync(cnt, 0, B * sizeof(int), stream);   // capture-legal
    dvs_partial<<<B * BLK_PER_B, 256, 0, stream>>>(Is, Ids, Zinv, mu,
                                                   ws, cnt, out);
}

// Round 16
// 75.333 us; speedup vs baseline: 3.0753x; 3.0753x over previous
//
#include <hip/hip_runtime.h>
#include <math.h>

// DVS forward: per-batch 6x6 normal-equation build + solve.
// B=64, image 512x640, border 5 -> interior rows [5,507), cols [5,635).
// R15 = R12 logic with lane = 2 cols (float2): halves the register window
// (14x2=28 VGPR vs 56), doubling schedulable headroom; 6 segments x 128 cols,
// 24576 waves (2x TLP, finer tail). Shuffles/row unchanged (6). Same
// branchless clamp dedup, XCD swizzle, RPT=8, Is/Zinv 3-slot rotation.
// Two kernels (fusion via device atomics regressed 4x in R14).

namespace {
constexpr int HI = 512, WI = 640, BRD = 5;
constexpr int RPT = 8;                 // center rows per wave
constexpr int TILES = 64;              // row tiles per (b,seg)
constexpr int WVS = 4;                 // waves per block
constexpr int BPS = TILES / WVS;       // 16 blocks per (b,seg)
constexpr int SEGS = 6;                // 6 segs x 128 cols (105 owned each)
constexpr int BLK_PER_B = SEGS * BPS;  // 96 partials per batch
constexpr float PXc = 600.0f, PYc = 600.0f, U0c = 320.0f, V0c = 256.0f;
constexpr float G1 = 2047.0f / 8418.0f * 600.0f;   // F*PX (PX==PY)
constexpr float G2 = 913.0f  / 8418.0f * 600.0f;
constexpr float G3 = 112.0f  / 8418.0f * 600.0f;
}

__device__ __forceinline__ float elem2(const float2 v, int q) {
    return q == 0 ? v.x : v.y;
}

__global__ __launch_bounds__(256) void dvs_partial(
    const float* __restrict__ Is, const float* __restrict__ Ids,
    const float* __restrict__ Zinv, float* __restrict__ ws)
{
    const int tid  = threadIdx.x;
    const int lane = tid & 63;
    const int wv   = tid >> 6;
    // XCD-chunked bijective swizzle (grid % 8 == 0): chunk c -> XCD c.
    int wg = blockIdx.x;
    if ((gridDim.x & 7) == 0) {
        const int chunk = gridDim.x >> 3;
        wg = (blockIdx.x & 7) * chunk + (blockIdx.x >> 3);
    }
    const int b   = wg / BLK_PER_B;
    const int rem = wg - b * BLK_PER_B;
    const int seg = rem / BPS;
    const int bg  = rem - seg * BPS;
    const int tile = bg * WVS + wv;
    const int r0 = BRD + tile * RPT;             // center rows r0..r0+7 (masked)

    // 6 segments: owned [lo, hi), wave cols [base, base+128).
    // Containment [lo-3, hi+2) in [base, base+128) verified per segment.
    const int lo   = 5 + 105 * seg;
    const int hi   = lo + 105;
    const int base = (seg == 0) ? 0   : (seg == 1) ? 102 : (seg == 2) ? 206
                   : (seg == 3) ? 312 : (seg == 4) ? 416 : 512;
    const int c0 = base + (lane << 1);

    // Branchless load-dedup (R12): clamp wasted lanes into the closure.
    const int cIds = min(max(c0, (lo - 3) & ~1), (hi + 1) & ~1);
    const int cIZ  = min(max(c0, lo & ~1), (hi - 1) & ~1);

    const size_t ofs = (size_t)b * (HI * WI);
    const float* __restrict__ Ib = Is   + ofs;
    const float* __restrict__ Db = Ids  + ofs;
    const float* __restrict__ Zb = Zinv + ofs;

    float msk[2], xk[2];
#pragma unroll
    for (int q = 0; q < 2; ++q) {
        const int c = c0 + q;
        msk[q] = (c >= lo && c < hi) ? 1.0f : 0.0f;
        xk[q]  = ((float)c - U0c) * (1.0f / PXc);
    }

    // ---- issue all 14 Ids window rows up front (float2, 28 VGPR) ----
    float2 win[14];
#pragma unroll
    for (int j = 0; j < 14; ++j) {
        const int rr = min(r0 - 3 + j, HI - 1);
        win[j] = *(const float2*)(Db + rr * WI + cIds);
    }
    // Is/Zinv: 3-slot rotation, 2-row lookahead (static indices under unroll)
    float2 isb[3], zvb[3];
    {
        const int ra = min(r0, HI - 1);
        const int rb = min(r0 + 1, HI - 1);
        isb[0] = *(const float2*)(Ib + ra * WI + cIZ);
        zvb[0] = *(const float2*)(Zb + ra * WI + cIZ);
        isb[1] = *(const float2*)(Ib + rb * WI + cIZ);
        zvb[1] = *(const float2*)(Zb + rb * WI + cIZ);
    }
    isb[2] = isb[0]; zvb[2] = zvb[0];

    float acc[27];
#pragma unroll
    for (int t = 0; t < 27; ++t) acc[t] = 0.0f;

    const int lm1 = (lane + 63) & 63, lm2 = (lane + 62) & 63;
    const int lp1 = (lane + 1) & 63,  lp2 = (lane + 2) & 63;

#pragma unroll
    for (int k = 0; k < RPT; ++k) {
        if (k < RPT - 2) {                        // prefetch row k+2 Is/Zinv
            const int rr = min(r0 + k + 2, HI - 1);
            isb[(k + 2) % 3] = *(const float2*)(Ib + rr * WI + cIZ);
            zvb[(k + 2) % 3] = *(const float2*)(Zb + rr * WI + cIZ);
        }
        const int rc = r0 + k;
        const float rmk = (rc < HI - BRD) ? 1.0f : 0.0f;
        const float2 a0 = win[k], a1 = win[k + 1], a2 = win[k + 2],
                     ct = win[k + 3], a4 = win[k + 4], a5 = win[k + 5],
                     a6 = win[k + 6];
        const float hl1 = __shfl(ct.y, lm1);  // col c0-1
        const float hl2 = __shfl(ct.x, lm1);  // col c0-2
        const float hl3 = __shfl(ct.y, lm2);  // col c0-3
        const float hr1 = __shfl(ct.x, lp1);  // col c0+2
        const float hr2 = __shfl(ct.y, lp1);  // col c0+3
        const float hr3 = __shfl(ct.x, lp2);  // col c0+4
        const float h[8] = {hl3, hl2, hl1, ct.x, ct.y, hr1, hr2, hr3};
        const float yv  = ((float)rc - V0c) * (1.0f / PYc);
        const float2 isV = isb[k % 3], zV = zvb[k % 3];
#pragma unroll
        for (int q = 0; q < 2; ++q) {
            const float m  = msk[q] * rmk;
            const float Ix = fmaf(G3, h[q + 6] - h[q],
                              fmaf(G2, h[q + 5] - h[q + 1],
                                   G1 * (h[q + 4] - h[q + 2]))) * m;
            const float Iy = fmaf(G3, elem2(a6, q) - elem2(a0, q),
                              fmaf(G2, elem2(a5, q) - elem2(a1, q),
                                   G1 * (elem2(a4, q) - elem2(a2, q)))) * m;
            const float Z  = elem2(zV, q);
            const float e  = elem2(isV, q) - elem2(ct, q);
            const float x  = xk[q], xy = x * yv;
            const float tt = x * Ix, uu = yv * Iy;
            float L[6];
            L[0] = Ix * Z;
            L[1] = Iy * Z;
            L[2] = -(tt + uu) * Z;
            L[3] = -(fmaf(yv, uu, Iy) + Ix * xy);   // -Ix*xy - (1+y^2)Iy
            L[4] = fmaf(x, tt, Ix) + Iy * xy;       // (1+x^2)Ix + Iy*xy
            L[5] = Iy * x - Ix * yv;
            int t = 0;
#pragma unroll
            for (int i = 0; i < 6; ++i)
#pragma unroll
                for (int j = i; j < 6; ++j)
                    acc[t++] += L[i] * L[j];
#pragma unroll
            for (int i = 0; i < 6; ++i) acc[21 + i] += L[i] * e;
        }
    }

    // wave butterfly reduce (deterministic)
#pragma unroll
    for (int t = 0; t < 27; ++t) {
        float v = acc[t];
        v += __shfl_xor(v, 1);  v += __shfl_xor(v, 2);  v += __shfl_xor(v, 4);
        v += __shfl_xor(v, 8);  v += __shfl_xor(v, 16); v += __shfl_xor(v, 32);
        acc[t] = v;
    }
    float outv = acc[0];
#pragma unroll
    for (int t = 1; t < 27; ++t) if (lane == t) outv = acc[t];

    __shared__ float red[WVS][28];
    if (lane < 27) red[wv][lane] = outv;
    __syncthreads();
    if (tid < 27) {
        float s = red[0][tid] + red[1][tid] + red[2][tid] + red[3][tid];
        ws[((size_t)b * BLK_PER_B + rem) * 27 + tid] = s;
    }
}

__global__ __launch_bounds__(64) void dvs_solve(
    const float* __restrict__ ws, const float* __restrict__ mu,
    float* __restrict__ out)
{
    const int b = blockIdx.x;
    const int lane = threadIdx.x;
    __shared__ double hsum[27];
    if (lane < 27) {
        double t = 0.0;
        for (int s = 0; s < BLK_PER_B; ++s)       // fixed order: deterministic
            t += (double)ws[((size_t)b * BLK_PER_B + s) * 27 + lane];
        hsum[lane] = t;
    }
    __syncthreads();
    if (lane == 0) {
        double A[6][7];
        int k = 0;
        for (int i = 0; i < 6; ++i)
            for (int j = i; j < 6; ++j) { A[i][j] = hsum[k]; A[j][i] = hsum[k]; ++k; }
        const double dm = 1.0 + (double)mu[b];
        for (int i = 0; i < 6; ++i) { A[i][i] *= dm; A[i][6] = hsum[21 + i]; }
        for (int col = 0; col < 6; ++col) {
            int p = col; double best = fabs(A[col][col]);
            for (int r = col + 1; r < 6; ++r) {
                const double vv = fabs(A[r][col]);
                if (vv > best) { best = vv; p = r; }
            }
            if (p != col)
                for (int cc = col; cc < 7; ++cc) {
                    const double t = A[col][cc]; A[col][cc] = A[p][cc]; A[p][cc] = t;
                }
            const double inv = 1.0 / A[col][col];
            for (int r = col + 1; r < 6; ++r) {
                const double f = A[r][col] * inv;
                for (int cc = col + 1; cc < 7; ++cc) A[r][cc] -= f * A[col][cc];
            }
        }
        double xs[6];
        for (int i = 5; i >= 0; --i) {
            double s = A[i][6];
            for (int j = i + 1; j < 6; ++j) s -= A[i][j] * xs[j];
            xs[i] = s / A[i][i];
        }
        for (int i = 0; i < 6; ++i) out[b * 6 + i] = (float)(-xs[i]);
    }
}

extern "C" void kernel_launch(void* const* d_in, const int* in_sizes, int n_in,
                              void* d_out, int out_size, void* d_ws, size_t ws_size,
                              hipStream_t stream)
{
    const float* Is   = (const float*)d_in[0];
    const float* Ids  = (const float*)d_in[1];
    const float* Zinv = (const float*)d_in[2];
    const float* mu   = (const float*)d_in[3];
    const int B = in_sizes[3];
    float* out = (float*)d_out;
    float* ws  = (float*)d_ws;

    dvs_partial<<<B * BLK_PER_B, 256, 0, stream>>>(Is, Ids, Zinv, ws);
    dvs_solve<<<B, 64, 0, stream>>>(ws, mu, out);
}

// Round 17
// 59.651 us; speedup vs baseline: 3.8838x; 1.2629x over previous
//
#include <hip/hip_runtime.h>
#include <math.h>

// DVS forward: per-batch 6x6 normal-equation build + solve.
// B=64, image 512x640, border 5 -> interior rows [5,507), cols [5,635).
// R16: async-pipelined Ids staging via global_load_lds (no VGPR round-trip).
// Block = 4 waves, 64-row x 256-col strip, 8-row chunks through a 24-slot
// circular LDS row buffer. Per chunk: stage 8 next rows (2 global_load_lds
// per wave) -> compute current chunk (wave computes 2 rows; vertical taps =
// ds_read_b128 from LDS, horizontal taps = shuffles on center row) -> one
// __syncthreads (its vmcnt drain completes the staged rows). Staging slots
// never collide with the read window (offset distance 4..21 mod 24).
// Is/Zinv: double-buffered register prefetch (clamped dedup addresses, R12).

namespace {
constexpr int HI = 512, WI = 640, BRD = 5;
constexpr int CH  = 8;                  // rows per chunk
constexpr int NCH = 8;                  // chunks per block strip
constexpr int ROWS = CH * NCH;          // 64 center rows per block
constexpr int SLOTS = 24;               // circular LDS row slots
constexpr int STRIPS = 8;               // 8*64=512 >= 502
constexpr int SEGS = 3;
constexpr int BLK_PER_B = SEGS * STRIPS;  // 24 partials per batch
constexpr float PXc = 600.0f, PYc = 600.0f, U0c = 320.0f, V0c = 256.0f;
constexpr float G1 = 2047.0f / 8418.0f * 600.0f;   // F*PX (PX==PY)
constexpr float G2 = 913.0f  / 8418.0f * 600.0f;
constexpr float G3 = 112.0f  / 8418.0f * 600.0f;
}

__device__ __forceinline__ float elem(const float4 v, int q) {
    return q == 0 ? v.x : (q == 1 ? v.y : (q == 2 ? v.z : v.w));
}

// async global->LDS: per-lane global addr, wave-uniform LDS base + lane*16
__device__ __forceinline__ void gload16(const float* g, float* l) {
    __builtin_amdgcn_global_load_lds(
        (const __attribute__((address_space(1))) void*)g,
        (__attribute__((address_space(3))) void*)l, 16, 0, 0);
}

__global__ __launch_bounds__(256) void dvs_partial(
    const float* __restrict__ Is, const float* __restrict__ Ids,
    const float* __restrict__ Zinv, float* __restrict__ ws)
{
    const int tid  = threadIdx.x;
    const int lane = tid & 63;
    const int wv   = tid >> 6;
    // XCD-chunked bijective swizzle (grid % 8 == 0): chunk c -> XCD c.
    int wg = blockIdx.x;
    if ((gridDim.x & 7) == 0) {
        const int chunk = gridDim.x >> 3;
        wg = (blockIdx.x & 7) * chunk + (blockIdx.x >> 3);
    }
    const int b   = wg / BLK_PER_B;
    const int rem = wg - b * BLK_PER_B;
    const int seg = rem / STRIPS;
    const int st  = rem - seg * STRIPS;
    const int S   = BRD + st * ROWS;             // strip's first center row

    const int base = (seg == 0) ? 0   : ((seg == 1) ? 200 : 384);
    const int lo   = (seg == 0) ? 5   : ((seg == 1) ? 252 : 452);
    const int hi   = (seg == 0) ? 252 : ((seg == 1) ? 452 : 635);
    const int c0 = base + (lane << 2);

    // Branchless load-dedup addresses (R12): clamp wasted lanes into closure.
    const int cIds = min(max(c0, (lo - 3) & ~3), (hi + 2) & ~3);
    const int cIZ  = min(max(c0, lo & ~3), (hi - 1) & ~3);

    const size_t ofs = (size_t)b * (HI * WI);
    const float* __restrict__ Ib = Is   + ofs;
    const float* __restrict__ Db = Ids  + ofs;
    const float* __restrict__ Zb = Zinv + ofs;

    float msk[4], xk[4];
#pragma unroll
    for (int q = 0; q < 4; ++q) {
        const int c = c0 + q;
        msk[q] = (c >= lo && c < hi) ? 1.0f : 0.0f;
        xk[q]  = ((float)c - U0c) * (1.0f / PXc);
    }

    __shared__ float tile[SLOTS][256];           // 24 KB circular row buffer
    __shared__ float red[4][28];

    // ---- prologue: stage window rows S-3 .. S+10 (logical offs 0..13) ----
#pragma unroll
    for (int j = 0; j < 4; ++j) {
        const int j2 = wv * 4 + j;               // wave-uniform
        if (j2 < 14) {
            const int r = min(S - 3 + j2, HI - 1);
            gload16(Db + r * WI + cIds, &tile[j2][0]);
        }
    }
    // Is/Zinv chunk-0 prefetch (wave rows: S + 2*wv + {0,1})
    float4 isb[2][2], zvb[2][2];
    {
        const int ra = min(S + 2 * wv, HI - 1);
        const int rb = min(S + 2 * wv + 1, HI - 1);
        isb[0][0] = *(const float4*)(Ib + ra * WI + cIZ);
        zvb[0][0] = *(const float4*)(Zb + ra * WI + cIZ);
        isb[0][1] = *(const float4*)(Ib + rb * WI + cIZ);
        zvb[0][1] = *(const float4*)(Zb + rb * WI + cIZ);
    }
    isb[1][0] = isb[0][0]; isb[1][1] = isb[0][1];
    zvb[1][0] = zvb[0][0]; zvb[1][1] = zvb[0][1];

    float acc[27];
#pragma unroll
    for (int t = 0; t < 27; ++t) acc[t] = 0.0f;

    const int lm = (lane + 63) & 63, lp = (lane + 1) & 63;

    __syncthreads();                             // prologue staging complete

#pragma unroll
    for (int t = 0; t < NCH; ++t) {
        // ---- stage chunk t+1's 8 new rows (logical offs 14+8t .. 21+8t) ----
        if (t < NCH - 1) {
#pragma unroll
            for (int j = 0; j < 2; ++j) {
                const int lofs = 14 + 8 * t + wv * 2 + j;   // wave-uniform
                const int r = min(S - 3 + lofs, HI - 1);
                gload16(Db + r * WI + cIds, &tile[lofs % SLOTS][0]);
            }
            // prefetch Is/Zinv for chunk t+1
            const int ra = min(S + 8 * (t + 1) + 2 * wv, HI - 1);
            const int rb = min(S + 8 * (t + 1) + 2 * wv + 1, HI - 1);
            isb[(t + 1) & 1][0] = *(const float4*)(Ib + ra * WI + cIZ);
            zvb[(t + 1) & 1][0] = *(const float4*)(Zb + ra * WI + cIZ);
            isb[(t + 1) & 1][1] = *(const float4*)(Ib + rb * WI + cIZ);
            zvb[(t + 1) & 1][1] = *(const float4*)(Zb + rb * WI + cIZ);
        }

        // ---- compute chunk t: wave's center rows rc = S+8t+2wv+{0,1} ----
#pragma unroll
        for (int i = 0; i < 2; ++i) {
            const int rc = S + 8 * t + 2 * wv + i;
            const float rmk = (rc < HI - BRD) ? 1.0f : 0.0f;
            const int bo = 8 * t + 2 * wv + i;   // logical off of row rc-3
            float4 w0 = *(const float4*)&tile[(bo + 0) % SLOTS][lane << 2];
            float4 w1 = *(const float4*)&tile[(bo + 1) % SLOTS][lane << 2];
            float4 w2 = *(const float4*)&tile[(bo + 2) % SLOTS][lane << 2];
            float4 ct = *(const float4*)&tile[(bo + 3) % SLOTS][lane << 2];
            float4 w4 = *(const float4*)&tile[(bo + 4) % SLOTS][lane << 2];
            float4 w5 = *(const float4*)&tile[(bo + 5) % SLOTS][lane << 2];
            float4 w6 = *(const float4*)&tile[(bo + 6) % SLOTS][lane << 2];
            const float hl1 = __shfl(ct.w, lm);   // col c0-1
            const float hl2 = __shfl(ct.z, lm);   // col c0-2
            const float hl3 = __shfl(ct.y, lm);   // col c0-3
            const float hr1 = __shfl(ct.x, lp);   // col c0+4
            const float hr2 = __shfl(ct.y, lp);   // col c0+5
            const float hr3 = __shfl(ct.z, lp);   // col c0+6
            const float h[10] = {hl3, hl2, hl1, ct.x, ct.y, ct.z, ct.w,
                                 hr1, hr2, hr3};
            const float yv  = ((float)rc - V0c) * (1.0f / PYc);
            const float4 isV = isb[t & 1][i], zV = zvb[t & 1][i];
#pragma unroll
            for (int q = 0; q < 4; ++q) {
                const float m  = msk[q] * rmk;
                const float Ix = fmaf(G3, h[q + 6] - h[q],
                                  fmaf(G2, h[q + 5] - h[q + 1],
                                       G1 * (h[q + 4] - h[q + 2]))) * m;
                const float Iy = fmaf(G3, elem(w6, q) - elem(w0, q),
                                  fmaf(G2, elem(w5, q) - elem(w1, q),
                                       G1 * (elem(w4, q) - elem(w2, q)))) * m;
                const float Z  = elem(zV, q);
                const float e  = elem(isV, q) - elem(ct, q);
                const float x  = xk[q], xy = x * yv;
                const float tt = x * Ix, uu = yv * Iy;
                float L[6];
                L[0] = Ix * Z;
                L[1] = Iy * Z;
                L[2] = -(tt + uu) * Z;
                L[3] = -(fmaf(yv, uu, Iy) + Ix * xy);
                L[4] = fmaf(x, tt, Ix) + Iy * xy;
                L[5] = Iy * x - Ix * yv;
                int a = 0;
#pragma unroll
                for (int ii = 0; ii < 6; ++ii)
#pragma unroll
                    for (int jj = ii; jj < 6; ++jj)
                        acc[a++] += L[ii] * L[jj];
#pragma unroll
                for (int ii = 0; ii < 6; ++ii) acc[21 + ii] += L[ii] * e;
            }
        }
        __syncthreads();   // drains staging vmcnt; protects circular slots
    }

    // wave butterfly reduce (deterministic)
#pragma unroll
    for (int t = 0; t < 27; ++t) {
        float v = acc[t];
        v += __shfl_xor(v, 1);  v += __shfl_xor(v, 2);  v += __shfl_xor(v, 4);
        v += __shfl_xor(v, 8);  v += __shfl_xor(v, 16); v += __shfl_xor(v, 32);
        acc[t] = v;
    }
    float outv = acc[0];
#pragma unroll
    for (int t = 1; t < 27; ++t) if (lane == t) outv = acc[t];

    if (lane < 27) red[wv][lane] = outv;
    __syncthreads();
    if (tid < 27) {
        float s = red[0][tid] + red[1][tid] + red[2][tid] + red[3][tid];
        ws[((size_t)b * BLK_PER_B + rem) * 27 + tid] = s;
    }
}

__global__ __launch_bounds__(64) void dvs_solve(
    const float* __restrict__ ws, const float* __restrict__ mu,
    float* __restrict__ out)
{
    const int b = blockIdx.x;
    const int lane = threadIdx.x;
    __shared__ double hsum[27];
    if (lane < 27) {
        double t = 0.0;
        for (int s = 0; s < BLK_PER_B; ++s)       // fixed order: deterministic
            t += (double)ws[((size_t)b * BLK_PER_B + s) * 27 + lane];
        hsum[lane] = t;
    }
    __syncthreads();
    if (lane == 0) {
        double A[6][7];
        int k = 0;
        for (int i = 0; i < 6; ++i)
            for (int j = i; j < 6; ++j) { A[i][j] = hsum[k]; A[j][i] = hsum[k]; ++k; }
        const double dm = 1.0 + (double)mu[b];
        for (int i = 0; i < 6; ++i) { A[i][i] *= dm; A[i][6] = hsum[21 + i]; }
        for (int col = 0; col < 6; ++col) {
            int p = col; double best = fabs(A[col][col]);
            for (int r = col + 1; r < 6; ++r) {
                const double vv = fabs(A[r][col]);
                if (vv > best) { best = vv; p = r; }
            }
            if (p != col)
                for (int cc = col; cc < 7; ++cc) {
                    const double t = A[col][cc]; A[col][cc] = A[p][cc]; A[p][cc] = t;
                }
            const double inv = 1.0 / A[col][col];
            for (int r = col + 1; r < 6; ++r) {
                const double f = A[r][col] * inv;
                for (int cc = col + 1; cc < 7; ++cc) A[r][cc] -= f * A[col][cc];
            }
        }
        double xs[6];
        for (int i = 5; i >= 0; --i) {
            double s = A[i][6];
            for (int j = i + 1; j < 6; ++j) s -= A[i][j] * xs[j];
            xs[i] = s / A[i][i];
        }
        for (int i = 0; i < 6; ++i) out[b * 6 + i] = (float)(-xs[i]);
    }
}

extern "C" void kernel_launch(void* const* d_in, const int* in_sizes, int n_in,
                              void* d_out, int out_size, void* d_ws, size_t ws_size,
                              hipStream_t stream)
{
    const float* Is   = (const float*)d_in[0];
    const float* Ids  = (const float*)d_in[1];
    const float* Zinv = (const float*)d_in[2];
    const float* mu   = (const float*)d_in[3];
    const int B = in_sizes[3];
    float* out = (float*)d_out;
    float* ws  = (float*)d_ws;

    dvs_partial<<<B * BLK_PER_B, 256, 0, stream>>>(Is, Ids, Zinv, ws);
    dvs_solve<<<B, 64, 0, stream>>>(ws, mu, out);
}

// Round 18
// 57.405 us; speedup vs baseline: 4.0358x; 1.0391x over previous
//
#include <hip/hip_runtime.h>
#include <math.h>

// DVS forward: per-batch 6x6 normal-equation build + solve.
// B=64, image 512x640, border 5 -> interior rows [5,507), cols [5,635).
// FINAL (revert to R12, session best 56.5us): RPT=8, 14-row register window
// issued up front, barrier-free hot loop, XCD-chunked bijective swizzle,
// branchless clamp load-dedup, Is/Zinv 3-slot rotation with 2-row lookahead,
// natural 64-VGPR allocation (the measured equilibrium: every structural
// perturbation -- occupancy up/down, bigger tiles, LDS staging, async DMA,
// atomic fusion -- regressed). Two kernels; f64 solve, deterministic.

namespace {
constexpr int HI = 512, WI = 640, BRD = 5;
constexpr int RPT = 8;                 // center rows per wave
constexpr int TILES = 64;              // tiles per (b,seg); 64*8=512>=502, tail masked
constexpr int WVS = 4;                 // waves per block
constexpr int BPS = TILES / WVS;       // 16 blocks per (b,seg)
constexpr int SEGS = 3;
constexpr int BLK_PER_B = SEGS * BPS;  // 48 partials per batch
constexpr float PXc = 600.0f, PYc = 600.0f, U0c = 320.0f, V0c = 256.0f;
constexpr float G1 = 2047.0f / 8418.0f * 600.0f;   // F*PX (PX==PY)
constexpr float G2 = 913.0f  / 8418.0f * 600.0f;
constexpr float G3 = 112.0f  / 8418.0f * 600.0f;
}

__device__ __forceinline__ float elem(const float4 v, int q) {
    return q == 0 ? v.x : (q == 1 ? v.y : (q == 2 ? v.z : v.w));
}

__global__ __launch_bounds__(256) void dvs_partial(
    const float* __restrict__ Is, const float* __restrict__ Ids,
    const float* __restrict__ Zinv, float* __restrict__ ws)
{
    const int tid  = threadIdx.x;
    const int lane = tid & 63;
    const int wv   = tid >> 6;
    // XCD-chunked bijective swizzle (grid % 8 == 0): chunk c -> XCD c.
    int wg = blockIdx.x;
    if ((gridDim.x & 7) == 0) {
        const int chunk = gridDim.x >> 3;
        wg = (blockIdx.x & 7) * chunk + (blockIdx.x >> 3);
    }
    const int b   = wg / BLK_PER_B;
    const int rem = wg - b * BLK_PER_B;
    const int seg = rem / BPS;
    const int bg  = rem - seg * BPS;
    const int tile = bg * WVS + wv;
    const int r0 = BRD + tile * RPT;             // center rows r0..r0+7 (masked)

    const int base = (seg == 0) ? 0   : ((seg == 1) ? 200 : 384);
    const int lo   = (seg == 0) ? 5   : ((seg == 1) ? 252 : 452);
    const int hi   = (seg == 0) ? 252 : ((seg == 1) ? 452 : 635);
    const int c0 = base + (lane << 2);

    // Branchless load-dedup addresses: clamp wasted lanes into the closure so
    // they re-fetch an in-closure cache line instead of dead lines. No branch
    // => no liveness extension => the 64-VGPR pipelined schedule survives.
    const int cIds = min(max(c0, (lo - 3) & ~3), (hi + 2) & ~3);
    const int cIZ  = min(max(c0, lo & ~3), (hi - 1) & ~3);

    const size_t ofs = (size_t)b * (HI * WI);
    const float* __restrict__ Ib = Is   + ofs;
    const float* __restrict__ Db = Ids  + ofs;
    const float* __restrict__ Zb = Zinv + ofs;

    float msk[4], xk[4];
#pragma unroll
    for (int q = 0; q < 4; ++q) {
        const int c = c0 + q;
        msk[q] = (c >= lo && c < hi) ? 1.0f : 0.0f;
        xk[q]  = ((float)c - U0c) * (1.0f / PXc);
    }

    // ---- issue all 14 Ids window rows up front (independent addresses) ----
    float4 win[14];
#pragma unroll
    for (int j = 0; j < 14; ++j) {
        const int rr = min(r0 - 3 + j, HI - 1);
        win[j] = *(const float4*)(Db + rr * WI + cIds);
    }
    // Is/Zinv: 3-slot rotation, 2-row lookahead (static indices under unroll)
    float4 isb[3], zvb[3];
    {
        const int ra = min(r0, HI - 1);
        const int rb = min(r0 + 1, HI - 1);
        isb[0] = *(const float4*)(Ib + ra * WI + cIZ);
        zvb[0] = *(const float4*)(Zb + ra * WI + cIZ);
        isb[1] = *(const float4*)(Ib + rb * WI + cIZ);
        zvb[1] = *(const float4*)(Zb + rb * WI + cIZ);
    }
    isb[2] = isb[0]; zvb[2] = zvb[0];

    float acc[27];
#pragma unroll
    for (int t = 0; t < 27; ++t) acc[t] = 0.0f;

    const int lm = (lane + 63) & 63, lp = (lane + 1) & 63;

#pragma unroll
    for (int k = 0; k < RPT; ++k) {
        if (k < RPT - 2) {                        // prefetch row k+2 Is/Zinv
            const int rr = min(r0 + k + 2, HI - 1);
            isb[(k + 2) % 3] = *(const float4*)(Ib + rr * WI + cIZ);
            zvb[(k + 2) % 3] = *(const float4*)(Zb + rr * WI + cIZ);
        }
        const int rc = r0 + k;
        const float rmk = (rc < HI - BRD) ? 1.0f : 0.0f;
        const float4 a0 = win[k], a1 = win[k + 1], a2 = win[k + 2],
                     ct = win[k + 3], a4 = win[k + 4], a5 = win[k + 5],
                     a6 = win[k + 6];
        const float hl1 = __shfl(ct.w, lm);   // col c0-1
        const float hl2 = __shfl(ct.z, lm);   // col c0-2
        const float hl3 = __shfl(ct.y, lm);   // col c0-3
        const float hr1 = __shfl(ct.x, lp);   // col c0+4
        const float hr2 = __shfl(ct.y, lp);   // col c0+5
        const float hr3 = __shfl(ct.z, lp);   // col c0+6
        const float h[10] = {hl3, hl2, hl1, ct.x, ct.y, ct.z, ct.w,
                             hr1, hr2, hr3};
        const float yv  = ((float)rc - V0c) * (1.0f / PYc);
        const float4 isV = isb[k % 3], zV = zvb[k % 3];
#pragma unroll
        for (int q = 0; q < 4; ++q) {
            const float m  = msk[q] * rmk;
            const float Ix = fmaf(G3, h[q + 6] - h[q],
                              fmaf(G2, h[q + 5] - h[q + 1],
                                   G1 * (h[q + 4] - h[q + 2]))) * m;
            const float Iy = fmaf(G3, elem(a6, q) - elem(a0, q),
                              fmaf(G2, elem(a5, q) - elem(a1, q),
                                   G1 * (elem(a4, q) - elem(a2, q)))) * m;
            const float Z  = elem(zV, q);
            const float e  = elem(isV, q) - elem(ct, q);
            const float x  = xk[q], xy = x * yv;
            const float tt = x * Ix, uu = yv * Iy;
            float L[6];
            L[0] = Ix * Z;
            L[1] = Iy * Z;
            L[2] = -(tt + uu) * Z;
            L[3] = -(fmaf(yv, uu, Iy) + Ix * xy);   // -Ix*xy - (1+y^2)Iy
            L[4] = fmaf(x, tt, Ix) + Iy * xy;       // (1+x^2)Ix + Iy*xy
            L[5] = Iy * x - Ix * yv;
            int t = 0;
#pragma unroll
            for (int i = 0; i < 6; ++i)
#pragma unroll
                for (int j = i; j < 6; ++j)
                    acc[t++] += L[i] * L[j];
#pragma unroll
            for (int i = 0; i < 6; ++i) acc[21 + i] += L[i] * e;
        }
    }

    // wave butterfly reduce (deterministic)
#pragma unroll
    for (int t = 0; t < 27; ++t) {
        float v = acc[t];
        v += __shfl_xor(v, 1);  v += __shfl_xor(v, 2);  v += __shfl_xor(v, 4);
        v += __shfl_xor(v, 8);  v += __shfl_xor(v, 16); v += __shfl_xor(v, 32);
        acc[t] = v;
    }
    float outv = acc[0];
#pragma unroll
    for (int t = 1; t < 27; ++t) if (lane == t) outv = acc[t];

    __shared__ float red[WVS][28];
    if (lane < 27) red[wv][lane] = outv;
    __syncthreads();
    if (tid < 27) {
        float s = red[0][tid] + red[1][tid] + red[2][tid] + red[3][tid];
        ws[(size_t)wg * 27 + tid] = s;
    }
}

__global__ __launch_bounds__(64) void dvs_solve(
    const float* __restrict__ ws, const float* __restrict__ mu,
    float* __restrict__ out)
{
    const int b = blockIdx.x;
    const int lane = threadIdx.x;
    __shared__ double hsum[27];
    if (lane < 27) {
        double t = 0.0;
        for (int s = 0; s < BLK_PER_B; ++s)       // fixed order: deterministic
            t += (double)ws[((size_t)b * BLK_PER_B + s) * 27 + lane];
        hsum[lane] = t;
    }
    __syncthreads();
    if (lane == 0) {
        double A[6][7];
        int k = 0;
        for (int i = 0; i < 6; ++i)
            for (int j = i; j < 6; ++j) { A[i][j] = hsum[k]; A[j][i] = hsum[k]; ++k; }
        const double dm = 1.0 + (double)mu[b];
        for (int i = 0; i < 6; ++i) { A[i][i] *= dm; A[i][6] = hsum[21 + i]; }
        for (int col = 0; col < 6; ++col) {
            int p = col; double best = fabs(A[col][col]);
            for (int r = col + 1; r < 6; ++r) {
                const double vv = fabs(A[r][col]);
                if (vv > best) { best = vv; p = r; }
            }
            if (p != col)
                for (int cc = col; cc < 7; ++cc) {
                    const double t = A[col][cc]; A[col][cc] = A[p][cc]; A[p][cc] = t;
                }
            const double inv = 1.0 / A[col][col];
            for (int r = col + 1; r < 6; ++r) {
                const double f = A[r][col] * inv;
                for (int cc = col + 1; cc < 7; ++cc) A[r][cc] -= f * A[col][cc];
            }
        }
        double xs[6];
        for (int i = 5; i >= 0; --i) {
            double s = A[i][6];
            for (int j = i + 1; j < 6; ++j) s -= A[i][j] * xs[j];
            xs[i] = s / A[i][i];
        }
        for (int i = 0; i < 6; ++i) out[b * 6 + i] = (float)(-xs[i]);
    }
}

extern "C" void kernel_launch(void* const* d_in, const int* in_sizes, int n_in,
                              void* d_out, int out_size, void* d_ws, size_t ws_size,
                              hipStream_t stream)
{
    const float* Is   = (const float*)d_in[0];
    const float* Ids  = (const float*)d_in[1];
    const float* Zinv = (const float*)d_in[2];
    const float* mu   = (const float*)d_in[3];
    const int B = in_sizes[3];
    float* out = (float*)d_out;
    float* ws  = (float*)d_ws;

    dvs_partial<<<B * BLK_PER_B, 256, 0, stream>>>(Is, Ids, Zinv, ws);
    dvs_solve<<<B, 64, 0, stream>>>(ws, mu, out);
}